// Round 3
// baseline (202.648 us; speedup 1.0000x reference)
//
#include <hip/hip_runtime.h>

#define NEGV -10000.0f

typedef _Float16 f16x8 __attribute__((ext_vector_type(8)));
typedef _Float16 f16x2 __attribute__((ext_vector_type(2)));
typedef float floatx4 __attribute__((ext_vector_type(4)));

// key (0..319) -> source sequence row. keys 0..63 local to query block nblk,
// keys 64..319 are the 256 global positions {0,61,62,63}+64j.
__device__ __forceinline__ int src_row(int key, int nblk) {
    if (key < 64) return nblk * 64 + key;
    int g = key - 64;
    int p = g & 3;
    return (g >> 2) * 64 + (p ? (60 + p) : 0);
}

__device__ __forceinline__ f16x8 cvt8(const float4& f0, const float4& f1) {
    f16x8 o;
    o[0] = (_Float16)f0.x; o[1] = (_Float16)f0.y;
    o[2] = (_Float16)f0.z; o[3] = (_Float16)f0.w;
    o[4] = (_Float16)f1.x; o[5] = (_Float16)f1.y;
    o[6] = (_Float16)f1.z; o[7] = (_Float16)f1.w;
    return o;
}

// Swapped-QK + key permutation L(t,n) = 32*(t>>1) + 8*(n>>2) + 4*(t&1) + (n&3):
//   acc[t][r] at lane (quad,m) = S[L(t, 4*quad+r)][qrow m]; pf[kc][4h+r] =
//   acc[2kc+h][r] is the PV A-fragment (pure in-lane cvt, no P round-trip).
// Round 3: K is NOT staged in LDS. The swapped-QK A-fragment is 8 contiguous
// floats per lane, so each wave loads K fragments directly from global (L2-
// resident; 4x re-read across waves is cheap, the staging barriers were not).
// LDS holds only the VT image; ONE barrier in the whole kernel.
__global__ __launch_bounds__(256, 3)
void sparse_attn_kernel(const float* __restrict__ Q, const float* __restrict__ K,
                        const float* __restrict__ V, const float* __restrict__ M,
                        float* __restrict__ O)
{
    // XCD swizzle: 4 whole heads per XCD so the head's K/V rows stay in L2.
    const int x    = blockIdx.x;
    const int bh   = (x & 7) * 4 + ((x >> 3) >> 6);   // 0..31
    const int nblk = (x >> 3) & 63;                   // query block in head
    const int b    = bh >> 4;

    const size_t hoff = (size_t)bh * (4096 * 64);
    const float* Qh = Q + hoff;
    const float* Kh = K + hoff;
    const float* Vh = V + hoff;
    float*       Oh = O + hoff;
    const float* Mb = M + (size_t)b * 4096;

    // VT image: slab (kc*4 + t) holds V^T frag for keys 32kc..+31 x dims
    // 16t..+15, XOR-swizzled by (t<<4) f16 for 2-way (free) writes.
    __shared__ _Float16 smem[20480];

    const int tid  = threadIdx.x;
    const int lane = tid & 63;
    const int wv   = tid >> 6;          // wave -> query rows wv*16..+15
    const int m    = lane & 15;
    const int quad = lane >> 4;
    const int cg   = tid & 15;          // V col granule (4 floats)
    const int pg   = tid >> 4;          // V key-pair sub-index (0..15)

    // ---- mask: 5 values per lane + all-ones fast-path ballot ----
    float mv2[5];
    unsigned long long bb = 0ull;
    #pragma unroll
    for (int s = 0; s < 5; ++s) {
        float mval = Mb[src_row(s * 64 + lane, nblk)];
        bb |= __ballot(mval == 0.0f);
        mv2[s] = (mval == 0.0f) ? NEGV : 0.0f;
    }

    // ---- Q fragments direct from global (fp16); B-operand of swapped QK ----
    const int qrow = nblk * 64 + wv * 16 + m;
    f16x8 qf[2];
    #pragma unroll
    for (int c = 0; c < 2; ++c) {
        const float* src = Qh + (size_t)qrow * 64 + c * 32 + quad * 8;
        float4 f0 = *(const float4*)src;
        float4 f1 = *(const float4*)(src + 4);
        qf[c] = cvt8(f0, f1);
    }

    // ---- V granule helpers: granule it = keys 32it..32it+31 ----
    auto v_load = [&](int it, float4& f0, float4& f1) {
        int l0 = 2 * (it * 16 + pg);
        f0 = *(const float4*)(Vh + (size_t)src_row(l0,     nblk) * 64 + cg * 4);
        f1 = *(const float4*)(Vh + (size_t)src_row(l0 + 1, nblk) * 64 + cg * 4);
    };
    auto vt_store = [&](int it, const float4& f0, const float4& f1) {
        int l0    = 2 * (it * 16 + pg);
        int kc2   = l0 >> 5;
        int q2    = (l0 & 31) >> 3;
        int j0    = l0 & 7;
        int td    = cg >> 2;
        int sw    = td << 4;
        int lbase = (kc2 * 4 + td) * 512 + q2 * 128 + (cg & 3) * 32 + j0;
        f16x2 pk0; pk0[0] = (_Float16)f0.x; pk0[1] = (_Float16)f1.x;
        *(f16x2*)(&smem[(lbase +  0) ^ sw]) = pk0;
        f16x2 pk1; pk1[0] = (_Float16)f0.y; pk1[1] = (_Float16)f1.y;
        *(f16x2*)(&smem[(lbase +  8) ^ sw]) = pk1;
        f16x2 pk2; pk2[0] = (_Float16)f0.z; pk2[1] = (_Float16)f1.z;
        *(f16x2*)(&smem[(lbase + 16) ^ sw]) = pk2;
        f16x2 pk3; pk3[0] = (_Float16)f0.w; pk3[1] = (_Float16)f1.w;
        *(f16x2*)(&smem[(lbase + 24) ^ sw]) = pk3;
    };

    // ---- QK tile: K A-fragment loaded directly from global (8 contiguous
    //      floats per lane), converted in-reg, 2 MFMA ----
    floatx4 acc[20] = {};
    auto qk_tile = [&](int t) {
        int lkey = 32 * (t >> 1) + 8 * (m >> 2) + 4 * (t & 1) + (m & 3);
        const float* src = Kh + (size_t)src_row(lkey, nblk) * 64 + quad * 8;
        float4 f0 = *(const float4*)src;
        float4 f1 = *(const float4*)(src + 4);
        float4 f2 = *(const float4*)(src + 32);
        float4 f3 = *(const float4*)(src + 36);
        acc[t] = __builtin_amdgcn_mfma_f32_16x16x32_f16(cvt8(f0, f1), qf[0], acc[t], 0, 0, 0);
        acc[t] = __builtin_amdgcn_mfma_f32_16x16x32_f16(cvt8(f2, f3), qf[1], acc[t], 0, 0, 0);
    };

    // ---- issue V granules 0..4; they land under the first QK half ----
    float4 va[5], vb[5];
    #pragma unroll
    for (int it = 0; it < 5; ++it) v_load(it, va[it], vb[it]);

    #pragma unroll
    for (int t = 0; t < 10; ++t) qk_tile(t);

    // ---- VT stores 0..4 (loads landed); frees va/vb for second batch ----
    #pragma unroll
    for (int it = 0; it < 5; ++it) vt_store(it, va[it], vb[it]);

    #pragma unroll
    for (int t = 10; t < 20; ++t) qk_tile(t);

    // ---- issue V granules 5..9; land under softmax ----
    #pragma unroll
    for (int it = 0; it < 5; ++it) v_load(5 + it, va[it], vb[it]);

    // ---- mask slow path (only when any position masked out) ----
    if (bb != 0ull) {
        #pragma unroll
        for (int t = 0; t < 20; ++t) {
            int lb = 32 * ((t >> 1) & 1) + 4 * (t & 1) + 8 * quad;
            #pragma unroll
            for (int r = 0; r < 4; ++r)
                acc[t][r] += __shfl(mv2[t >> 2], lb + r, 64);
        }
    }

    // ---- softmax max (lane holds one full q-row; reduce over quads) ----
    float rmax = -3e38f;
    #pragma unroll
    for (int t = 0; t < 20; ++t)
        #pragma unroll
        for (int r = 0; r < 4; ++r)
            rmax = fmaxf(rmax, acc[t][r]);
    rmax = fmaxf(rmax, __shfl_xor(rmax, 16, 64));
    rmax = fmaxf(rmax, __shfl_xor(rmax, 32, 64));

    // ---- VT stores 5..9 ----
    #pragma unroll
    for (int it = 0; it < 5; ++it) vt_store(5 + it, va[it], vb[it]);

    // ---- exp + rowsum ----
    float rsum = 0.f;
    #pragma unroll
    for (int t = 0; t < 20; ++t)
        #pragma unroll
        for (int r = 0; r < 4; ++r) {
            float e = __expf(acc[t][r] - rmax);
            acc[t][r] = e;                 // unnormalized; 1/sum at epilogue
            rsum += e;
        }
    rsum += __shfl_xor(rsum, 16, 64);
    rsum += __shfl_xor(rsum, 32, 64);
    float rinv = 1.0f / rsum;

    // ---- P fragments: pure in-lane cvt; acc dies here ----
    f16x8 pf[10];
    #pragma unroll
    for (int k2 = 0; k2 < 10; ++k2) {
        #pragma unroll
        for (int r = 0; r < 4; ++r) {
            pf[k2][r]     = (_Float16)acc[2 * k2][r];
            pf[k2][4 + r] = (_Float16)acc[2 * k2 + 1][r];
        }
    }

    __syncthreads();   // ONLY barrier: VT image complete

    // ---- PV: 40 MFMA ----
    floatx4 oacc[4] = {};
    #pragma unroll
    for (int k2 = 0; k2 < 10; ++k2) {
        #pragma unroll
        for (int t = 0; t < 4; ++t) {
            f16x8 vf = *(const f16x8*)(&smem[(k2 * 4 + t) * 512 + ((lane * 8) ^ (t << 4))]);
            oacc[t] = __builtin_amdgcn_mfma_f32_16x16x32_f16(pf[k2], vf, oacc[t], 0, 0, 0);
        }
    }

    // ---- epilogue: apply 1/rowsum, store fp32 ----
    float rinvr[4];
    #pragma unroll
    for (int r = 0; r < 4; ++r)
        rinvr[r] = __shfl(rinv, quad * 4 + r, 64);
    #pragma unroll
    for (int t = 0; t < 4; ++t)
        #pragma unroll
        for (int r = 0; r < 4; ++r)
            Oh[(size_t)(nblk * 64 + wv * 16 + quad * 4 + r) * 64 + t * 16 + m] =
                oacc[t][r] * rinvr[r];
}

extern "C" void kernel_launch(void* const* d_in, const int* in_sizes, int n_in,
                              void* d_out, int out_size, void* d_ws, size_t ws_size,
                              hipStream_t stream) {
    const float* q    = (const float*)d_in[0];
    const float* k    = (const float*)d_in[1];
    const float* v    = (const float*)d_in[2];
    const float* mask = (const float*)d_in[3];
    float* out = (float*)d_out;
    (void)in_sizes; (void)n_in; (void)out_size; (void)d_ws; (void)ws_size;
    sparse_attn_kernel<<<2 * 16 * 64, 256, 0, stream>>>(q, k, v, mask, out);
}

// Round 4
// 147.989 us; speedup vs baseline: 1.3694x; 1.3694x over previous
//
#include <hip/hip_runtime.h>

#define NEGV -10000.0f

typedef _Float16 f16x8 __attribute__((ext_vector_type(8)));
typedef _Float16 f16x2 __attribute__((ext_vector_type(2)));
typedef float floatx4 __attribute__((ext_vector_type(4)));

// key (0..319) -> source sequence row. keys 0..63 local to query block nblk,
// keys 64..319 are the 256 global positions {0,61,62,63}+64j.
__device__ __forceinline__ int src_row(int key, int nblk) {
    if (key < 64) return nblk * 64 + key;
    int g = key - 64;
    int p = g & 3;
    return (g >> 2) * 64 + (p ? (60 + p) : 0);
}

__device__ __forceinline__ f16x8 cvt8(const float4& f0, const float4& f1) {
    f16x8 o;
    o[0] = (_Float16)f0.x; o[1] = (_Float16)f0.y;
    o[2] = (_Float16)f0.z; o[3] = (_Float16)f0.w;
    o[4] = (_Float16)f1.x; o[5] = (_Float16)f1.y;
    o[6] = (_Float16)f1.z; o[7] = (_Float16)f1.w;
    return o;
}

// Async 16B global->LDS DMA: zero VGPR footprint, per-lane GLOBAL address,
// LDS dest = wave-uniform base + lane*16 (m104/m173 semantics).
__device__ __forceinline__ void load_lds16(const float* g, float* l) {
    __builtin_amdgcn_global_load_lds(
        (const __attribute__((address_space(1))) void*)g,
        (__attribute__((address_space(3))) void*)l, 16, 0, 0);
}

// Swapped-QK + key permutation L(t,n) = 32*(t>>1) + 8*(n>>2) + 4*(t&1) + (n&3):
//   acc[t][r] at lane (quad,m) = S[L(t,4*quad+r)][qrow m]; pf[kc][4h+r] =
//   acc[2kc+h][r] is the PV A-fragment (pure in-lane cvt, no P round-trip).
// Round 4: K staged as FP32 via global_load_lds (async DMA, no VGPR cap on
// in-flight loads -> all 20 staging loads overlap; round-3 showed VGPR-landing
// gathers serialize). f32->f16 cvt deferred to fragment read. K image slot
// within slab t: phys = n*16 + (g ^ n)  (XOR folded into the DMA *source*
// address; linear LDS dest) -> QK's stride-256B reads are conflict-free.
// All 10 V granules (80 VGPR) issued before B1, resident through QK
// (launch_bounds(256,2): 2 blocks/CU is the 80KB LDS cap anyway, so the
// register budget is free). VT f16 image (40KB) overlays K slabs 0..9 at B2.
__global__ __launch_bounds__(256, 2)
void sparse_attn_kernel(const float* __restrict__ Q, const float* __restrict__ K,
                        const float* __restrict__ V, const float* __restrict__ M,
                        float* __restrict__ O)
{
    // XCD swizzle: 4 whole heads per XCD so the head's K/V rows stay in L2.
    const int x    = blockIdx.x;
    const int bh   = (x & 7) * 4 + ((x >> 3) >> 6);   // 0..31
    const int nblk = (x >> 3) & 63;                   // query block in head
    const int b    = bh >> 4;

    const size_t hoff = (size_t)bh * (4096 * 64);
    const float* Qh = Q + hoff;
    const float* Kh = K + hoff;
    const float* Vh = V + hoff;
    float*       Oh = O + hoff;
    const float* Mb = M + (size_t)b * 4096;

    __shared__ float smemK[20480];            // 80 KB: K fp32 image (20 slabs x 4KB)
    _Float16* VTb = (_Float16*)smemK;         // after B2: VT f16 image (40 KB overlay)

    const int tid  = threadIdx.x;
    const int lane = tid & 63;
    const int wv   = tid >> 6;          // wave -> query rows wv*16..+15
    const int m    = lane & 15;
    const int quad = lane >> 4;
    const int cg   = tid & 15;          // V col granule (4 floats)
    const int pg   = tid >> 4;          // V key-pair sub-index (0..15)

    // ---- K staging: 20 async DMA, zero VGPR. Slot P = i*256 + tid;
    //      slab t = P>>8; phys-in-slab q = P&255; n = q>>4; g = (q&15)^n. ----
    #pragma unroll
    for (int i = 0; i < 20; ++i) {
        int P    = i * 256 + tid;
        int t    = P >> 8;
        int q    = P & 255;
        int n    = q >> 4;
        int g    = (q & 15) ^ n;
        int lkey = 32 * (t >> 1) + 8 * (n >> 2) + 4 * (t & 1) + (n & 3);
        const float* src = Kh + (size_t)src_row(lkey, nblk) * 64 + g * 4;
        load_lds16(src, smemK + (i * 256 + wv * 64) * 4);   // wave-uniform dest
    }

    // ---- mask: 5 values per lane + all-ones fast-path ballot ----
    float mv2[5];
    unsigned long long bb = 0ull;
    #pragma unroll
    for (int s = 0; s < 5; ++s) {
        float mval = Mb[src_row(s * 64 + lane, nblk)];
        bb |= __ballot(mval == 0.0f);
        mv2[s] = (mval == 0.0f) ? NEGV : 0.0f;
    }

    // ---- Q fragments direct from global (fp16); B-operand of swapped QK ----
    const int qrow = nblk * 64 + wv * 16 + m;
    f16x8 qf[2];
    #pragma unroll
    for (int c = 0; c < 2; ++c) {
        const float* src = Qh + (size_t)qrow * 64 + c * 32 + quad * 8;
        float4 f0 = *(const float4*)src;
        float4 f1 = *(const float4*)(src + 4);
        qf[c] = cvt8(f0, f1);
    }

    // ---- ALL 10 V granules issued now (80 VGPR, resident through QK) ----
    float4 va[10], vb[10];
    #pragma unroll
    for (int it = 0; it < 10; ++it) {
        int l0 = 2 * (it * 16 + pg);
        va[it] = *(const float4*)(Vh + (size_t)src_row(l0,     nblk) * 64 + cg * 4);
        vb[it] = *(const float4*)(Vh + (size_t)src_row(l0 + 1, nblk) * 64 + cg * 4);
    }

    __syncthreads();   // B1: K DMA drained (vmcnt0) + all waves' writes visible

    // ---- swapped QK^T: 40 MFMA; A-frag = 2x ds_read_b128 fp32 + cvt ----
    floatx4 acc[20] = {};
    #pragma unroll
    for (int t = 0; t < 20; ++t) {
        #pragma unroll
        for (int c = 0; c < 2; ++c) {
            int g0 = c * 8 + 2 * quad;
            int q0 = m * 16 + (g0 ^ m);
            int q1 = m * 16 + ((g0 + 1) ^ m);
            float4 f0 = *(const float4*)(&smemK[t * 1024 + q0 * 4]);
            float4 f1 = *(const float4*)(&smemK[t * 1024 + q1 * 4]);
            acc[t] = __builtin_amdgcn_mfma_f32_16x16x32_f16(cvt8(f0, f1), qf[c], acc[t], 0, 0, 0);
        }
    }

    __syncthreads();   // B2: all QK reads of K image done -> VT may overlay

    // ---- VT stores: all 10 granules (frees the 80 V regs) ----
    #pragma unroll
    for (int it = 0; it < 10; ++it) {
        int l0    = 2 * (it * 16 + pg);
        int kc2   = l0 >> 5;
        int q2    = (l0 & 31) >> 3;
        int j0    = l0 & 7;
        int td    = cg >> 2;
        int sw    = td << 4;
        int lbase = (kc2 * 4 + td) * 512 + q2 * 128 + (cg & 3) * 32 + j0;
        const float4 f0 = va[it], f1 = vb[it];
        f16x2 pk0; pk0[0] = (_Float16)f0.x; pk0[1] = (_Float16)f1.x;
        *(f16x2*)(&VTb[(lbase +  0) ^ sw]) = pk0;
        f16x2 pk1; pk1[0] = (_Float16)f0.y; pk1[1] = (_Float16)f1.y;
        *(f16x2*)(&VTb[(lbase +  8) ^ sw]) = pk1;
        f16x2 pk2; pk2[0] = (_Float16)f0.z; pk2[1] = (_Float16)f1.z;
        *(f16x2*)(&VTb[(lbase + 16) ^ sw]) = pk2;
        f16x2 pk3; pk3[0] = (_Float16)f0.w; pk3[1] = (_Float16)f1.w;
        *(f16x2*)(&VTb[(lbase + 24) ^ sw]) = pk3;
    }

    // ---- mask slow path (only when any position masked out) ----
    if (bb != 0ull) {
        #pragma unroll
        for (int t = 0; t < 20; ++t) {
            int lb = 32 * ((t >> 1) & 1) + 4 * (t & 1) + 8 * quad;
            #pragma unroll
            for (int r = 0; r < 4; ++r)
                acc[t][r] += __shfl(mv2[t >> 2], lb + r, 64);
        }
    }

    // ---- softmax: lane holds one full q-row (80 keys); reduce over quads ----
    float rmax = -3e38f;
    #pragma unroll
    for (int t = 0; t < 20; ++t)
        #pragma unroll
        for (int r = 0; r < 4; ++r)
            rmax = fmaxf(rmax, acc[t][r]);
    rmax = fmaxf(rmax, __shfl_xor(rmax, 16, 64));
    rmax = fmaxf(rmax, __shfl_xor(rmax, 32, 64));
    float rsum = 0.f;
    #pragma unroll
    for (int t = 0; t < 20; ++t)
        #pragma unroll
        for (int r = 0; r < 4; ++r) {
            float e = __expf(acc[t][r] - rmax);
            acc[t][r] = e;
            rsum += e;
        }
    rsum += __shfl_xor(rsum, 16, 64);
    rsum += __shfl_xor(rsum, 32, 64);
    const float rinv = 1.0f / rsum;   // valid per-lane for q-row m

    // ---- P fragments: in-lane cvt with 1/rowsum FOLDED IN (normalized P) ----
    f16x8 pf[10];
    #pragma unroll
    for (int k2 = 0; k2 < 10; ++k2) {
        #pragma unroll
        for (int r = 0; r < 4; ++r) {
            pf[k2][r]     = (_Float16)(acc[2 * k2][r]     * rinv);
            pf[k2][4 + r] = (_Float16)(acc[2 * k2 + 1][r] * rinv);
        }
    }

    __syncthreads();   // B3: VT image complete (stores were issued pre-softmax)

    // ---- PV: 40 MFMA ----
    floatx4 oacc[4] = {};
    #pragma unroll
    for (int k2 = 0; k2 < 10; ++k2) {
        #pragma unroll
        for (int t = 0; t < 4; ++t) {
            f16x8 vf = *(const f16x8*)(&VTb[(k2 * 4 + t) * 512 + ((lane * 8) ^ (t << 4))]);
            oacc[t] = __builtin_amdgcn_mfma_f32_16x16x32_f16(pf[k2], vf, oacc[t], 0, 0, 0);
        }
    }

    // ---- epilogue: P was pre-normalized, plain stores ----
    #pragma unroll
    for (int t = 0; t < 4; ++t)
        #pragma unroll
        for (int r = 0; r < 4; ++r)
            Oh[(size_t)(nblk * 64 + wv * 16 + quad * 4 + r) * 64 + t * 16 + m] =
                oacc[t][r];
}

extern "C" void kernel_launch(void* const* d_in, const int* in_sizes, int n_in,
                              void* d_out, int out_size, void* d_ws, size_t ws_size,
                              hipStream_t stream) {
    const float* q    = (const float*)d_in[0];
    const float* k    = (const float*)d_in[1];
    const float* v    = (const float*)d_in[2];
    const float* mask = (const float*)d_in[3];
    float* out = (float*)d_out;
    (void)in_sizes; (void)n_in; (void)out_size; (void)d_ws; (void)ws_size;
    sparse_attn_kernel<<<2 * 16 * 64, 256, 0, stream>>>(q, k, v, mask, out);
}